// Round 7
// baseline (326.715 us; speedup 1.0000x reference)
//
#include <hip/hip_runtime.h>
#include <hip/hip_bf16.h>
#include <stdint.h>

// VQ nearest-codebook: B=8,N=4096,C=256,K=8192
// R15 = R14 (barrier-free, per-wave private B streams) +
//  (1) A-fragments loaded DIRECTLY global->regs per-lane (aF[4][8], 128 VGPR;
//      identical bits to the old LDS path) -> A out of LDS, per-step LDS
//      traffic halves to 4 B ds_read_b128 (32KB/CU ~= 385cyc < MFMA 620cyc);
//  (2) amdgpu_waves_per_eu(1,2): R13's (2) set only the MIN (allocator kept
//      4 waves/EU = 128-reg cap); (1,2) caps max at 2 waves/EU = 256-reg
//      budget for the ~245-reg demand;
//  (3) prefetch depth 2: ring-4 private B buffers, WAITV(4) at step top
//      (only B(t+1) newer than B(t) -> B(t) guaranteed complete), hiding the
//      full L2 latency that R14's WAITV(0) exposed each step;
//  (4) cbsq copied once to LDS (32KB, one prologue barrier) -> vmcnt pure.
// LDS = 128KB B-ring + 32KB cq = 160KB (AITER attn precedent at 160KB).
// Output mapping/keys/records IDENTICAL to verified R10-R14 - absmax must be 0.

#define M_ROWS 32768   // B*N
#define KCODES 8192
#define CDIM   256
#define BM 128         // rows per block
#define BNT 256        // codes per tile
#define BK 32
#define NTILES 32      // KCODES / BNT
#define NREC 32        // records per row (each = top-2 over a 256-code subset)
#define MARGIN 0.75f   // >> hi-GEMM err (~0.32) + 2x key quantization (0.125)

typedef _Float16 f16x8 __attribute__((ext_vector_type(8)));
typedef _Float16 f16x4 __attribute__((ext_vector_type(4)));
typedef float    f32x4 __attribute__((ext_vector_type(4)));

#define WAITV(N) asm volatile("s_waitcnt vmcnt(" #N ")" ::: "memory")

__device__ __forceinline__ unsigned umin2(unsigned a, unsigned b) { return a < b ? a : b; }
__device__ __forceinline__ unsigned umax2(unsigned a, unsigned b) { return a > b ? a : b; }

// ---------------- prep: fp16 hi (scaled by 64) + row sq-norms ----------------
__global__ void vq_prep(const float* __restrict__ x, const float* __restrict__ cb,
                        _Float16* __restrict__ xhi, _Float16* __restrict__ cbhi,
                        float* __restrict__ xsq, float* __restrict__ cbsq) {
  const int wave = threadIdx.x >> 6, lane = threadIdx.x & 63;
  const int row = blockIdx.x * 4 + wave;     // one wave per row
  const float* src;
  _Float16* dhi;
  float* dsq;
  if (row < M_ROWS) {
    src = x + (size_t)row * CDIM;  dhi = xhi + (size_t)row * CDIM;  dsq = xsq + row;
  } else {
    const int r = row - M_ROWS;
    src = cb + (size_t)r * CDIM;   dhi = cbhi + (size_t)r * CDIM;   dsq = cbsq + r;
  }
  const float4 v = *(const float4*)(src + lane * 4);
  f16x4 h;
  h[0] = (_Float16)(v.x * 64.0f); h[1] = (_Float16)(v.y * 64.0f);
  h[2] = (_Float16)(v.z * 64.0f); h[3] = (_Float16)(v.w * 64.0f);
  *(f16x4*)(dhi + lane * 4) = h;
  float s = v.x * v.x + v.y * v.y + v.z * v.z + v.w * v.w;
  #pragma unroll
  for (int off = 32; off > 0; off >>= 1) s += __shfl_down(s, off, 64);
  if (lane == 0) *dsq = s;
}

// ---------------- pass1: A-in-regs hi GEMM + top-2 int-key records ----------------
__device__ __forceinline__ void gl16p(const void* g, void* l) {
  __builtin_amdgcn_global_load_lds(
      (const __attribute__((address_space(1))) unsigned int*)g,
      (__attribute__((address_space(3))) unsigned int*)l, 16, 0, 0);
}

__global__ __launch_bounds__(512) __attribute__((amdgpu_waves_per_eu(1, 2)))
void vq_pass1(
    const _Float16* __restrict__ xhi, const _Float16* __restrict__ cbhi,
    const float* __restrict__ cbsqg, uint2* __restrict__ srec) {
  extern __shared__ char smem[];
  _Float16* sB  = (_Float16*)smem;             // 8 waves x 4 bufs x 2048 elems = 128 KB
  float*    sCq = (float*)(smem + 131072);     // 8192 floats = 32 KB (full cbsq copy)

  const int tid  = threadIdx.x;
  const int wave = tid >> 6, lane = tid & 63;
  const int quad = lane >> 4, l15 = lane & 15;
  const int mbase = blockIdx.x * BM;
  const int wrow = (wave >> 2) * 64;    // row half
  const int q    = wave & 3;            // col quarter
  const int wcol = q * 64;

  // B staging geometry (R2's measured-zero-conflict pattern): row stride 64B.
  const int srl  = lane >> 2;
  const int scol = (((lane & 3) ^ ((lane >> 3) & 3)) << 3);
  const int fcol = ((quad ^ ((l15 >> 1) & 3)) << 3);

  _Float16* sBw = sB + wave * 8192;     // this wave's private 16 KB (4 x 2048 elems)

  // stage this wave's 64x32 B slice for (nts,kss) into private ring buffer buf
  auto stageB = [&](int nts, int kss, int buf) {
    const int c0 = nts * BNT + wcol;
    const int kofs = kss * BK;
    _Float16* dst = sBw + buf * 2048;
    #pragma unroll
    for (int t = 0; t < 4; ++t)
      gl16p(cbhi + (size_t)(c0 + t * 16 + srl) * CDIM + kofs + scol, dst + t * 512);
  };

  // ---- A fragments: direct per-lane global loads (same bits as old LDS path).
  // aF[mf][kk] = xhi[mbase+wrow+mf*16+l15][kk*32+quad*8 .. +7]
  f16x8 aF[4][8];
  #pragma unroll
  for (int mf = 0; mf < 4; ++mf) {
    const _Float16* arow = xhi + (size_t)(mbase + wrow + mf * 16 + l15) * CDIM;
    #pragma unroll
    for (int kk = 0; kk < 8; ++kk)
      aF[mf][kk] = *(const f16x8*)(arow + kk * 32 + quad * 8);
  }
  asm volatile("" ::: "memory");   // pin aF loads before the staging sequence

  // ---- cbsq -> LDS once (each wave stages its linear 4KB slice: 4 gl16)
  {
    const float* srcq = cbsqg + wave * 1024;
    float* dstq = sCq + wave * 1024;
    #pragma unroll
    for (int t = 0; t < 4; ++t)
      gl16p(srcq + t * 256 + lane * 4, dstq + t * 256);
  }
  // prologue B prefetch: steps 0 and 1
  stageB(0, 0, 0);
  stageB(0, 1, 1);
  // drain aF (32) + cq (4) [oldest 36 of 44], leave B0,B1 in flight
  WAITV(8);
  __builtin_amdgcn_s_barrier();    // cq visible to all waves; only barrier
  asm volatile("" ::: "memory");

  unsigned k1[4][4], k2[4][4];

  for (int nt = 0; nt < NTILES; ++nt) {
    const bool lastnt = (nt == NTILES - 1);
    if ((nt & 3) == 0) {   // open subchunk (4 nt x 64 cols = 256 codes / record)
      #pragma unroll
      for (int mf = 0; mf < 4; ++mf)
        #pragma unroll
        for (int i = 0; i < 4; ++i) { k1[mf][i] = 0x7fffffffu; k2[mf][i] = 0x7fffffffu; }
    }

    f32x4 acc[4][4];
    #pragma unroll
    for (int mf = 0; mf < 4; ++mf)
      #pragma unroll
      for (int nf = 0; nf < 4; ++nf) {
        f32x4 z = {0.0f, 0.0f, 0.0f, 0.0f};
        acc[mf][nf] = z;
      }

    #pragma unroll
    for (int ks = 0; ks < 8; ++ks) {
      // ---- top-of-step wait: B(t) done (only B(t+1) is newer = 4 loads);
      // tail of last tile has fewer in flight.
      if (ks == 7 && lastnt) { WAITV(0); } else { WAITV(4); }
      asm volatile("" ::: "memory");
      // ---- stage step t+2 into ring buf (t+2)&3 = (ks+2)&3 (8|nt => period-4 clean)
      if (ks <= 5)            stageB(nt, ks + 2, (ks + 2) & 3);
      else if (!lastnt) {
        if (ks == 6)          stageB(nt + 1, 0, 0);
        else                  stageB(nt + 1, 1, 1);
      }

      // ---- compute step t from private ring buffer ks&3 (A already in regs)
      const _Float16* sBc = sBw + (ks & 3) * 2048;
      __builtin_amdgcn_s_setprio(1);
      #pragma unroll
      for (int nf = 0; nf < 4; ++nf) {
        const f16x8 bh = *(const f16x8*)(sBc + (nf * 16 + l15) * BK + fcol);
        #pragma unroll
        for (int mf = 0; mf < 4; ++mf)
          acc[mf][nf] = __builtin_amdgcn_mfma_f32_16x16x32_f16(aF[mf][ks], bh, acc[mf][nf], 0, 0, 0);
      }
      __builtin_amdgcn_s_setprio(0);
    }

    // int-key top-2 insert: key = (uint)(16*v + 32768) << 13 | col
    // v = cbsq - 2*dot; acc = 4096*dot => 16*v = (16*cbsq+32768) - acc/128
    #pragma unroll
    for (int nf = 0; nf < 4; ++nf) {
      const int cwl = wcol + nf * 16 + l15;
      const int col = nt * BNT + cwl;               // global code (C/D: col = lane&15)
      const float cq16 = fmaf(sCq[col], 16.0f, 32768.0f);
      #pragma unroll
      for (int mf = 0; mf < 4; ++mf)
        #pragma unroll
        for (int i = 0; i < 4; ++i) {
          const float kf = fmaf(acc[mf][nf][i], -0.0078125f, cq16);
          const unsigned key = ((unsigned)kf << 13) | (unsigned)col;
          k2[mf][i] = umin2(k2[mf][i], umax2(k1[mf][i], key));
          k1[mf][i] = umin2(k1[mf][i], key);
        }
    }

    if ((nt & 3) == 3) {   // close subchunk: 16-lane top-2 butterfly merge, store record
      const int g = (nt >> 2) * 4 + q;              // 0..31
      #pragma unroll
      for (int mf = 0; mf < 4; ++mf)
        #pragma unroll
        for (int i = 0; i < 4; ++i) {
          unsigned a1 = k1[mf][i], a2 = k2[mf][i];
          #pragma unroll
          for (int m = 1; m <= 8; m <<= 1) {
            const unsigned o1 = (unsigned)__shfl_xor((int)a1, m, 64);
            const unsigned o2 = (unsigned)__shfl_xor((int)a2, m, 64);
            a2 = umin2(umin2(a2, o2), umax2(a1, o1));
            a1 = umin2(a1, o1);
          }
          if (l15 == 0) {
            const int rl = wrow + mf * 16 + quad * 4 + i;   // C/D row (0..127)
            uint2 r; r.x = a1; r.y = a2;
            srec[(size_t)(mbase + rl) * NREC + g] = r;
          }
        }
    }
  }
}

// ---------------- finalize: exact fp32 dots for margin candidates ----------------
__global__ void vq_finalize(const float* __restrict__ x, const float* __restrict__ cb,
                            const float* __restrict__ xsq, const float* __restrict__ cbsq,
                            const uint2* __restrict__ srec,
                            float* __restrict__ outIdx, float* __restrict__ outDist,
                            float* __restrict__ codes) {
  const int wave = threadIdx.x >> 6, lane = threadIdx.x & 63;
  const int row = blockIdx.x * 4 + wave;    // one wave per row
  uint2 rec;
  if (lane < NREC) rec = srec[(size_t)row * NREC + lane];
  else { rec.x = 0x7fffffffu; rec.y = 0x7fffffffu; }
  const float v1 = (float)(rec.x >> 13) * 0.0625f - 2048.0f;
  const float v2 = (float)(rec.y >> 13) * 0.0625f - 2048.0f;
  const int c1 = (int)(rec.x & 8191u);
  const int c2 = (int)(rec.y & 8191u);

  float gm = v1;
  #pragma unroll
  for (int m = 1; m <= 32; m <<= 1) gm = fminf(gm, __shfl_xor(gm, m, 64));
  const float thr = gm + MARGIN;
  unsigned long long mask1 = __ballot(v1 <= thr);
  unsigned long long mask2 = __ballot(v2 <= thr);

  const float4 xv = *(const float4*)(x + (size_t)row * CDIM + lane * 4);
  const float xq = xsq[row];
  float best = __builtin_inff(); int bidx = 1 << 30;

  #pragma unroll
  for (int pass = 0; pass < 2; ++pass) {
    unsigned long long m = pass ? mask2 : mask1;
    const int fi = pass ? c2 : c1;
    while (m) {
      const int g = __builtin_ctzll((long long)m); m &= m - 1;
      const int ci = __shfl(fi, g, 64);
      const float4 cv = *(const float4*)(cb + (size_t)ci * CDIM + lane * 4);
      float s = xv.x * cv.x + xv.y * cv.y + xv.z * cv.z + xv.w * cv.w;
      #pragma unroll
      for (int mm = 1; mm <= 32; mm <<= 1) s += __shfl_xor(s, mm, 64);
      const float dist = xq + cbsq[ci] - 2.0f * s;
      if (dist < best || (dist == best && ci < bidx)) { best = dist; bidx = ci; }
    }
  }

  if (lane == 0) { outIdx[row] = (float)bidx; outDist[row] = best; }
  const float4 cw = *(const float4*)(cb + (size_t)bidx * CDIM + lane * 4);
  *(float4*)(codes + (size_t)row * CDIM + lane * 4) = cw;
}

extern "C" void kernel_launch(void* const* d_in, const int* in_sizes, int n_in,
                              void* d_out, int out_size, void* d_ws, size_t ws_size,
                              hipStream_t stream) {
  const float* x  = (const float*)d_in[0];   // [8,4096,256] fp32
  const float* cb = (const float*)d_in[1];   // [8192,256] fp32
  float* out = (float*)d_out;                // codes | idx | dist

  char* w = (char*)d_ws;                     // ~29.2 MB
  _Float16* xhi  = (_Float16*)(w);                 // 16 MB
  _Float16* cbhi = (_Float16*)(w + 16777216);      //  4 MB
  float*    xsq  = (float*)   (w + 20971520);      // 128 KB
  float*    cbsq = (float*)   (w + 21102592);      //  32 KB
  uint2*    srec = (uint2*)   (w + 21135360);      //  8 MB (32768*32*8B)

  vq_prep<<<(M_ROWS + KCODES) / 4, 256, 0, stream>>>(x, cb, xhi, cbhi, xsq, cbsq);
  const size_t smem = 131072 + 32768;  // B ring 128K + cbsq copy 32K = 160 KB
  vq_pass1<<<dim3(M_ROWS / BM), 512, smem, stream>>>(xhi, cbhi, cbsq, srec);
  vq_finalize<<<M_ROWS / 4, 256, 0, stream>>>(x, cb, xsq, cbsq, srec,
                                              out + 8388608, out + 8421376, out);
}

// Round 8
// 280.808 us; speedup vs baseline: 1.1635x; 1.1635x over previous
//
#include <hip/hip_runtime.h>
#include <hip/hip_bf16.h>
#include <stdint.h>

// VQ nearest-codebook: B=8,N=4096,C=256,K=8192
// R16 = R14 (barrier-free, private per-wave B, A in LDS) +
//  (1) anti-phase skew: waves 4-7 (the 2nd wave on each SIMD) s_sleep ~640cyc
//      after the prologue barrier. R14's 1790cyc/step == serial sum of
//      MFMA 660 + LDS 770 + VALU: in-phase waves convoy on each pipe.
//      Half-step skew lets one wave's MFMA cover its partner's ds_read phase;
//      setprio preserves the separation. Zero reg cost, timing-only.
//  (2) ring-3 private B (12KB/wave, LDS=160KB total incl. 64KB A) with
//      counted vmcnt: default WAITV(8) certifies B(t) while B(t+1),B(t+2)
//      fly; WAITV(12) at the cq step; 4/0 at the tail. No forced retire of
//      a just-issued load anywhere in steady state.
//  (3) clean occupancy attrs (NO __launch_bounds__, which lowers to the same
//      LLVM attr and appears to squash amdgpu_waves_per_eu - R13/R15 both
//      ignored): flat_work_group_size(512,512) + waves_per_eu(1,2).
//      Diagnostic: VGPR_Count>112 next round => attr honored.
// Math/output mapping identical to verified R10-R15 (absmax=0 throughout).

#define M_ROWS 32768   // B*N
#define KCODES 8192
#define CDIM   256
#define BM 128         // rows per block
#define BNT 256        // codes per tile
#define BK 32
#define NTILES 32      // KCODES / BNT
#define NREC 32        // records per row (each = top-2 over a 256-code subset)
#define MARGIN 0.75f   // >> hi-GEMM err (~0.32) + 2x key quantization (0.125)

typedef _Float16 f16x8 __attribute__((ext_vector_type(8)));
typedef _Float16 f16x4 __attribute__((ext_vector_type(4)));
typedef float    f32x4 __attribute__((ext_vector_type(4)));

#define WAITV(N) asm volatile("s_waitcnt vmcnt(" #N ")" ::: "memory")

__device__ __forceinline__ unsigned umin2(unsigned a, unsigned b) { return a < b ? a : b; }
__device__ __forceinline__ unsigned umax2(unsigned a, unsigned b) { return a > b ? a : b; }

// ---------------- prep: fp16 hi (scaled by 64) + row sq-norms ----------------
__global__ void vq_prep(const float* __restrict__ x, const float* __restrict__ cb,
                        _Float16* __restrict__ xhi, _Float16* __restrict__ cbhi,
                        float* __restrict__ xsq, float* __restrict__ cbsq) {
  const int wave = threadIdx.x >> 6, lane = threadIdx.x & 63;
  const int row = blockIdx.x * 4 + wave;     // one wave per row
  const float* src;
  _Float16* dhi;
  float* dsq;
  if (row < M_ROWS) {
    src = x + (size_t)row * CDIM;  dhi = xhi + (size_t)row * CDIM;  dsq = xsq + row;
  } else {
    const int r = row - M_ROWS;
    src = cb + (size_t)r * CDIM;   dhi = cbhi + (size_t)r * CDIM;   dsq = cbsq + r;
  }
  const float4 v = *(const float4*)(src + lane * 4);
  f16x4 h;
  h[0] = (_Float16)(v.x * 64.0f); h[1] = (_Float16)(v.y * 64.0f);
  h[2] = (_Float16)(v.z * 64.0f); h[3] = (_Float16)(v.w * 64.0f);
  *(f16x4*)(dhi + lane * 4) = h;
  float s = v.x * v.x + v.y * v.y + v.z * v.z + v.w * v.w;
  #pragma unroll
  for (int off = 32; off > 0; off >>= 1) s += __shfl_down(s, off, 64);
  if (lane == 0) *dsq = s;
}

// ---------------- pass1: A-resident hi GEMM + top-2 int-key records ----------------
__device__ __forceinline__ void gl16p(const void* g, void* l) {
  __builtin_amdgcn_global_load_lds(
      (const __attribute__((address_space(1))) unsigned int*)g,
      (__attribute__((address_space(3))) unsigned int*)l, 16, 0, 0);
}

__global__ __attribute__((amdgpu_flat_work_group_size(512, 512), amdgpu_waves_per_eu(1, 2)))
void vq_pass1(
    const _Float16* __restrict__ xhi, const _Float16* __restrict__ cbhi,
    const float* __restrict__ cbsqg, uint2* __restrict__ srec) {
  extern __shared__ char smem[];
  _Float16* sA = (_Float16*)smem;                 // 128 x 256 fp16 = 64 KB (shared, RO)
  _Float16* sB = (_Float16*)(smem + 65536);       // 8 waves x 3 bufs x 2048 elems = 96 KB

  const int tid  = threadIdx.x;
  const int wave = tid >> 6, lane = tid & 63;
  const int quad = lane >> 4, l15 = lane & 15;
  const int mbase = blockIdx.x * BM;
  const int wrow = (wave >> 2) * 64;    // row half
  const int q    = wave & 3;            // col quarter
  const int wcol = q * 64;

  // ---- stage A once (FIFO-first: 8 gl16/wave)
  {
    const int ar = lane >> 5;            // row within pair
    const int as = lane & 31;            // 16B slot
    #pragma unroll
    for (int t = 0; t < 8; ++t) {
      const int rb  = (wave * 8 + t) * 2;
      const int row = rb + ar;
      const int slot = as ^ (row & 7);
      gl16p(xhi + (size_t)(mbase + row) * CDIM + slot * 8, sA + rb * CDIM);
    }
  }

  // B staging geometry (R2's measured-zero-conflict pattern): row stride 64B.
  const int srl  = lane >> 2;
  const int scol = (((lane & 3) ^ ((lane >> 3) & 3)) << 3);
  const int fcol = ((quad ^ ((l15 >> 1) & 3)) << 3);
  const int asw  = l15 & 7;             // A frag de-swizzle

  _Float16* sBw = sB + wave * 6144;     // this wave's private 12 KB (3 x 2048 elems)

  // stage this wave's 64x32 B slice for (nts,kss) into private buffer at offs
  auto stageB = [&](int nts, int kss, int offs) {
    const int c0 = nts * BNT + wcol;
    const int kofs = kss * BK;
    _Float16* dst = sBw + offs;
    #pragma unroll
    for (int t = 0; t < 4; ++t)
      gl16p(cbhi + (size_t)(c0 + t * 16 + srl) * CDIM + kofs + scol, dst + t * 512);
  };

  // prologue: FIFO = [A x8][B0 x4][B1 x4][cq0 x4]
  stageB(0, 0, 0);
  stageB(0, 1, 2048);
  float cq_cur[4], cq_nxt[4];
  #pragma unroll
  for (int j = 0; j < 4; ++j) cq_cur[j] = cbsqg[wcol + j * 16 + l15];
  // certify A (keep B0,B1,cq0 = 12 in flight), barrier for shared sA. Only barrier.
  WAITV(12);
  __builtin_amdgcn_s_barrier();
  asm volatile("" ::: "memory");
  // anti-phase skew: 2nd wave of each SIMD sleeps ~half a step
  if (wave & 4) { asm volatile("s_sleep 10"); }

  // ring-3 rotating offsets: r0 = buf of t, r1 = t+1, r2 = t+2 (mod 3)
  int r0 = 0, r1 = 2048, r2 = 4096;

  unsigned k1[4][4], k2[4][4];

  for (int nt = 0; nt < NTILES; ++nt) {
    const bool lastnt = (nt == NTILES - 1);
    if ((nt & 3) == 0) {   // open subchunk (4 nt x 64 cols = 256 codes / record)
      #pragma unroll
      for (int mf = 0; mf < 4; ++mf)
        #pragma unroll
        for (int i = 0; i < 4; ++i) { k1[mf][i] = 0x7fffffffu; k2[mf][i] = 0x7fffffffu; }
    }

    f32x4 acc[4][4];
    #pragma unroll
    for (int mf = 0; mf < 4; ++mf)
      #pragma unroll
      for (int nf = 0; nf < 4; ++nf) {
        f32x4 z = {0.0f, 0.0f, 0.0f, 0.0f};
        acc[mf][nf] = z;
      }

    #pragma unroll
    for (int ks = 0; ks < 8; ++ks) {
      // ---- stage step t+2 (t = nt*8+ks) into ring slot r2; cq at ks==6
      if (ks <= 5) {
        stageB(nt, ks + 2, r2);
        WAITV(8);              // certify B(t); keep B(t+1),B(t+2)
      } else if (ks == 6) {
        if (!lastnt) {
          stageB(nt + 1, 0, r2);
          #pragma unroll
          for (int j = 0; j < 4; ++j)
            cq_nxt[j] = cbsqg[(nt + 1) * BNT + wcol + j * 16 + l15];
          WAITV(12);           // certify B(t); keep B(t+1),B(t+2),cq
        } else {
          WAITV(4);            // tail: only B(t+1) may remain
        }
      } else {  // ks == 7
        if (!lastnt) {
          stageB(nt + 1, 1, r2);
          WAITV(8);            // certify B(t)+cq; keep B(t+1),B(t+2)
        } else {
          WAITV(0);            // very last step
        }
      }

      // ---- compute step t from ring slot r0
      const _Float16* sBc = sBw + r0;
      const int aslot = (ks * 4 + quad) ^ asw;       // 16B slot in resident A
      f16x8 ah[4];
      #pragma unroll
      for (int mf = 0; mf < 4; ++mf)
        ah[mf] = *(const f16x8*)(sA + (wrow + mf * 16 + l15) * CDIM + aslot * 8);
      __builtin_amdgcn_s_setprio(1);
      #pragma unroll
      for (int nf = 0; nf < 4; ++nf) {
        const f16x8 bh = *(const f16x8*)(sBc + (nf * 16 + l15) * BK + fcol);
        #pragma unroll
        for (int mf = 0; mf < 4; ++mf)
          acc[mf][nf] = __builtin_amdgcn_mfma_f32_16x16x32_f16(ah[mf], bh, acc[mf][nf], 0, 0, 0);
      }
      __builtin_amdgcn_s_setprio(0);

      // rotate ring: r_i tracks (t+i) mod 3
      { const int tmp = r0; r0 = r1; r1 = r2; r2 = tmp; }
    }

    // int-key top-2 insert: key = (uint)(16*v + 32768) << 13 | col
    // v = cbsq - 2*dot; acc = 4096*dot => 16*v = (16*cbsq+32768) - acc/128
    #pragma unroll
    for (int nf = 0; nf < 4; ++nf) {
      const int col = nt * BNT + wcol + nf * 16 + l15;   // global code (C/D: col = lane&15)
      const float cq16 = fmaf(cq_cur[nf], 16.0f, 32768.0f);
      #pragma unroll
      for (int mf = 0; mf < 4; ++mf)
        #pragma unroll
        for (int i = 0; i < 4; ++i) {
          const float kf = fmaf(acc[mf][nf][i], -0.0078125f, cq16);
          const unsigned key = ((unsigned)kf << 13) | (unsigned)col;
          k2[mf][i] = umin2(k2[mf][i], umax2(k1[mf][i], key));
          k1[mf][i] = umin2(k1[mf][i], key);
        }
    }

    if ((nt & 3) == 3) {   // close subchunk: 16-lane top-2 butterfly merge, store record
      const int g = (nt >> 2) * 4 + q;              // 0..31
      #pragma unroll
      for (int mf = 0; mf < 4; ++mf)
        #pragma unroll
        for (int i = 0; i < 4; ++i) {
          unsigned a1 = k1[mf][i], a2 = k2[mf][i];
          #pragma unroll
          for (int m = 1; m <= 8; m <<= 1) {
            const unsigned o1 = (unsigned)__shfl_xor((int)a1, m, 64);
            const unsigned o2 = (unsigned)__shfl_xor((int)a2, m, 64);
            a2 = umin2(umin2(a2, o2), umax2(a1, o1));
            a1 = umin2(a1, o1);
          }
          if (l15 == 0) {
            const int rl = wrow + mf * 16 + quad * 4 + i;   // C/D row (0..127)
            uint2 r; r.x = a1; r.y = a2;
            srec[(size_t)(mbase + rl) * NREC + g] = r;
          }
        }
    }

    #pragma unroll
    for (int j = 0; j < 4; ++j) cq_cur[j] = cq_nxt[j];
  }
}

// ---------------- finalize: exact fp32 dots for margin candidates ----------------
__global__ void vq_finalize(const float* __restrict__ x, const float* __restrict__ cb,
                            const float* __restrict__ xsq, const float* __restrict__ cbsq,
                            const uint2* __restrict__ srec,
                            float* __restrict__ outIdx, float* __restrict__ outDist,
                            float* __restrict__ codes) {
  const int wave = threadIdx.x >> 6, lane = threadIdx.x & 63;
  const int row = blockIdx.x * 4 + wave;    // one wave per row
  uint2 rec;
  if (lane < NREC) rec = srec[(size_t)row * NREC + lane];
  else { rec.x = 0x7fffffffu; rec.y = 0x7fffffffu; }
  const float v1 = (float)(rec.x >> 13) * 0.0625f - 2048.0f;
  const float v2 = (float)(rec.y >> 13) * 0.0625f - 2048.0f;
  const int c1 = (int)(rec.x & 8191u);
  const int c2 = (int)(rec.y & 8191u);

  float gm = v1;
  #pragma unroll
  for (int m = 1; m <= 32; m <<= 1) gm = fminf(gm, __shfl_xor(gm, m, 64));
  const float thr = gm + MARGIN;
  unsigned long long mask1 = __ballot(v1 <= thr);
  unsigned long long mask2 = __ballot(v2 <= thr);

  const float4 xv = *(const float4*)(x + (size_t)row * CDIM + lane * 4);
  const float xq = xsq[row];
  float best = __builtin_inff(); int bidx = 1 << 30;

  #pragma unroll
  for (int pass = 0; pass < 2; ++pass) {
    unsigned long long m = pass ? mask2 : mask1;
    const int fi = pass ? c2 : c1;
    while (m) {
      const int g = __builtin_ctzll((long long)m); m &= m - 1;
      const int ci = __shfl(fi, g, 64);
      const float4 cv = *(const float4*)(cb + (size_t)ci * CDIM + lane * 4);
      float s = xv.x * cv.x + xv.y * cv.y + xv.z * cv.z + xv.w * cv.w;
      #pragma unroll
      for (int mm = 1; mm <= 32; mm <<= 1) s += __shfl_xor(s, mm, 64);
      const float dist = xq + cbsq[ci] - 2.0f * s;
      if (dist < best || (dist == best && ci < bidx)) { best = dist; bidx = ci; }
    }
  }

  if (lane == 0) { outIdx[row] = (float)bidx; outDist[row] = best; }
  const float4 cw = *(const float4*)(cb + (size_t)bidx * CDIM + lane * 4);
  *(float4*)(codes + (size_t)row * CDIM + lane * 4) = cw;
}

extern "C" void kernel_launch(void* const* d_in, const int* in_sizes, int n_in,
                              void* d_out, int out_size, void* d_ws, size_t ws_size,
                              hipStream_t stream) {
  const float* x  = (const float*)d_in[0];   // [8,4096,256] fp32
  const float* cb = (const float*)d_in[1];   // [8192,256] fp32
  float* out = (float*)d_out;                // codes | idx | dist

  char* w = (char*)d_ws;                     // ~29.2 MB
  _Float16* xhi  = (_Float16*)(w);                 // 16 MB
  _Float16* cbhi = (_Float16*)(w + 16777216);      //  4 MB
  float*    xsq  = (float*)   (w + 20971520);      // 128 KB
  float*    cbsq = (float*)   (w + 21102592);      //  32 KB
  uint2*    srec = (uint2*)   (w + 21135360);      //  8 MB (32768*32*8B)

  vq_prep<<<(M_ROWS + KCODES) / 4, 256, 0, stream>>>(x, cb, xhi, cbhi, xsq, cbsq);
  const size_t smem = 65536 + 98304;  // A 64K + private B ring-3 96K = 160 KB
  vq_pass1<<<dim3(M_ROWS / BM), 512, smem, stream>>>(xhi, cbhi, cbsq, srec);
  vq_finalize<<<M_ROWS / 4, 256, 0, stream>>>(x, cb, xsq, cbsq, srec,
                                              out + 8388608, out + 8421376, out);
}